// Round 5
// baseline (2727.280 us; speedup 1.0000x reference)
//
#include <hip/hip_runtime.h>
#include <hip/hip_bf16.h>

// ---------------------------------------------------------------------------
// TGN neighbor attention. Key algebra:
//   softmax over HEADS(=2) per edge  =>  att0 = sigmoid(s0-s1), att1 = 1-att0
//   => only the DIFFERENCE dual Ad = A1-A0 is needed for scores, where
//      A_h[i] = sum_o q_h[o] * Wk[o,i]  (dual trick), i in [0,384)
//   => Ad = qsign @ Wk with qsign = [-q0 | +q1]  (single pass)
//   s1-s0 = (Ad.keyv + qbkd) / sqrt(128),  qbkd = qsign.bk
//   S_0,arr = att0-weighted sums; S_1,arr = (unweighted) - S_0,arr
//   satt1 = 20 - satt0
//   logits = sum_r CW_r @ S_r + satt0*cb0 + (20-satt0)*cb1 + c10
// Kd: dtype detect (node_data i32/i64, mask u8/i32/i64/f32)
// K0: constants. Kc: v_emb/r_emb -> bf16 tables in ws (working set ~154 MB,
//     L2/L3-serviced). K1: per-node qsign -> Ad table (bf16) + qbkd.
// K2 (rewritten this round): 3-pass batched edge phase — pass A computes all
//     dot partials (ILP), pass B one batched 60-shfl butterfly (independent
//     chains pipeline at DS throughput instead of serial 200cy/edge), pass C
//     batched sigmoids+accums. __launch_bounds__(256,4) caps VGPR at 128 for
//     4 waves/SIMD (was 168 VGPR -> ~2).
// ---------------------------------------------------------------------------

#define N_NODES 100000
#define EMB 128
#define NBR 20
#define CLS 10

// ws float-offsets for the small constant region
#define OFF_QBIAS 0            // 128
#define OFF_CW    128          // 6*10*128 = 7680, layout ((arr*2+h)*10+c)*128+d
#define OFF_CB    (128 + 7680) // 20: [h][c]
#define OFF_C10   (OFF_CB + 20)// 10
#define OFF_FLAGS 8000         // 2 ints (byte off 32000)
// byte offsets of the big ws tables
#define OFF_ABC 32768ULL                          // 100000*384*2 = 76.8 MB
#define OFF_QBK (OFF_ABC + 100000ULL * 384 * 2)   // 0.4 MB
#define OFF_VBF (OFF_QBK + 100000ULL * 4)         // 25.6 MB
#define OFF_RBF (OFF_VBF + 100000ULL * 128 * 2)   // 25.6 MB

#define RSQRT128 0.08838834764831845f

// round-to-nearest-even f32 -> bf16 bits
__device__ __forceinline__ unsigned short f2bf(float x) {
  unsigned u = __float_as_uint(x);
  return (unsigned short)((u + 0x7fffu + ((u >> 16) & 1u)) >> 16);
}
// unpack 2 bf16 (packed little-endian in a uint) -> float2
__device__ __forceinline__ float2 unpack_bf2(unsigned u) {
  float2 f;
  f.x = __uint_as_float(u << 16);
  f.y = __uint_as_float(u & 0xffff0000u);
  return f;
}

// ---- dtype-flexible loads (flags decided by tgn_detect at runtime) --------
__device__ __forceinline__ int load_node(const void* nd, size_t idx, int is64) {
  if (is64) return (int)((const long long*)nd)[idx];
  return ((const int*)nd)[idx];
}
// mode: 0=u8, 1=i32, 2=i64, 3=f32
__device__ __forceinline__ int load_mask(const void* m, size_t idx, int mode) {
  if (mode == 0) return ((const unsigned char*)m)[idx] != 0;
  if (mode == 1) return ((const int*)m)[idx] != 0;
  if (mode == 2) return ((const long long*)m)[idx] != 0;
  return ((const float*)m)[idx] != 0.0f;
}

// ---------------------------------------------------------------------------
__global__ __launch_bounds__(256) void tgn_detect(
    const int* __restrict__ nd, const unsigned char* __restrict__ m,
    int* __restrict__ flags)
{
  __shared__ int s_odd, s_b123, s_b4, s_bgt;
  const int tid = threadIdx.x;
  if (tid == 0) { s_odd = 0; s_b123 = 0; s_b4 = 0; s_bgt = 0; }
  __syncthreads();
  int odd = 0;
  for (int i = 2 * tid + 1; i < 4096; i += 512) odd |= nd[i];
  int b123 = 0, b4 = 0, bgt = 0;
  for (int i = tid * 4; i < 8192; i += 1024) {
    b123 |= m[i + 1] | m[i + 2] | m[i + 3];
    bgt |= (m[i] > 1) | (m[i + 1] > 1) | (m[i + 2] > 1) | (m[i + 3] > 1);
  }
  for (int i = tid * 8 + 4; i < 8192; i += 2048) b4 |= m[i];
  if (odd) atomicOr(&s_odd, 1);
  if (b123) atomicOr(&s_b123, 1);
  if (b4) atomicOr(&s_b4, 1);
  if (bgt) atomicOr(&s_bgt, 1);
  __syncthreads();
  if (tid == 0) {
    flags[0] = (s_odd == 0) ? 1 : 0;  // node_data is int64
    flags[1] = s_bgt ? 3 : (s_b123 ? 0 : (s_b4 ? 1 : 2));
  }
}

// ---------------------------------------------------------------------------
// Kc: fp32 -> packed bf16x2 table conversion (grid-stride over float2 pairs)
// ---------------------------------------------------------------------------
__global__ __launch_bounds__(256) void tgn_cvt(
    const float* __restrict__ src, unsigned* __restrict__ dst, int npair)
{
  int i = blockIdx.x * 256 + threadIdx.x;
  const int stride = gridDim.x * 256;
  for (; i < npair; i += stride) {
    float2 f = ((const float2*)src)[i];
    dst[i] = (unsigned)f2bf(f.x) | ((unsigned)f2bf(f.y) << 16);
  }
}

// ---------------------------------------------------------------------------
// K0: one block. qbias = Wq[:,128:]@cos(time_b)+bq ; M = Wc@Wo ;
// CW[arr*2+h] = M_h @ Wv[h-rows, arr-block] ; cb[h]=M_h@bv_h ; c10=Wc@bo+bc
// ---------------------------------------------------------------------------
__global__ __launch_bounds__(256) void tgn_k0_prep(
    const float* __restrict__ Wq, const float* __restrict__ bq,
    const float* __restrict__ time_b,
    const float* __restrict__ Wv, const float* __restrict__ bv,
    const float* __restrict__ Wo, const float* __restrict__ bo,
    const float* __restrict__ Wc, const float* __restrict__ bc,
    float* __restrict__ wsf)
{
  __shared__ float ccos[128];
  __shared__ float sM[10 * 128];
  const int tid = threadIdx.x;
  if (tid < 128) ccos[tid] = cosf(time_b[tid]);
  __syncthreads();
  if (tid < 128) {
    float s = bq[tid];
    for (int j = 0; j < 128; ++j) s += Wq[tid * 256 + 128 + j] * ccos[j];
    wsf[OFF_QBIAS + tid] = s;
  }
  for (int idx = tid; idx < 1280; idx += 256) {   // M = Wc @ Wo  (10x128)
    int c = idx >> 7, i = idx & 127;
    float s = 0.f;
    for (int k = 0; k < 128; ++k) s += Wc[c * 128 + k] * Wo[k * 128 + i];
    sM[idx] = s;
  }
  __syncthreads();
  for (int idx = tid; idx < 7680; idx += 256) {   // CW composites
    int r = idx / 1280;
    int c = (idx >> 7) % 10;
    int d = idx & 127;
    int arr = r >> 1, h = r & 1;
    float s = 0.f;
    for (int k = 0; k < 64; ++k)
      s += sM[c * 128 + h * 64 + k] * Wv[(h * 64 + k) * 384 + arr * 128 + d];
    wsf[OFF_CW + idx] = s;
  }
  if (tid < 20) {                                  // cb[h][c]
    int h = tid / 10, c = tid % 10;
    float s = 0.f;
    for (int k = 0; k < 64; ++k) s += sM[c * 128 + h * 64 + k] * bv[h * 64 + k];
    wsf[OFF_CB + tid] = s;
  }
  if (tid < 10) {                                  // c10 = Wc@bo + bc
    float s = 0.f;
    for (int k = 0; k < 128; ++k) s += Wc[tid * 128 + k] * bo[k];
    wsf[OFF_C10 + tid] = s + bc[tid];
  }
}

// ---------------------------------------------------------------------------
// K1: 32 nodes/block.
// Phase1: q = Wq1@ve + qbias (Wq1 staged in 4 K-chunks [128][33]); store
//         qsign into q_s (negate dims<64 = head0).
// Phase2: Ad[32][384] = qsign @ Wk, Wk staged in 8 chunks of 16 rows
//         ([16][385]); store bf16 to ABC[n*384+i].
// QBK[n] = qsign . bk.   Dynamic LDS 12416 floats = 49664 B (<64 KB cap).
// ---------------------------------------------------------------------------
__global__ __launch_bounds__(256) void tgn_k1_abc(
    const void* __restrict__ node_data, const float* __restrict__ v_emb,
    const float* __restrict__ Wq, const float* __restrict__ Wk,
    const float* __restrict__ bk, const float* __restrict__ wsf,
    const int* __restrict__ flags, unsigned short* __restrict__ ABC,
    float* __restrict__ QBK)
{
  extern __shared__ float smem[];
  float* WqS = smem;          // [128][33]
  float* veS = smem + 4224;   // [32][128]
  float* WkS = smem;          // [16][385]
  float* q_s = smem + 8320;   // [32][128]
  __shared__ int sv[32];
  const int tid = threadIdx.x;
  const int base = blockIdx.x * 32;  // 3125 * 32 == 100000 exactly
  const int nd64 = flags[0];

  if (tid < 32) sv[tid] = load_node(node_data, (size_t)(base + tid) * 4, nd64);
  __syncthreads();
  for (int idx = tid; idx < 4096; idx += 256) {
    int n = idx >> 7, i = idx & 127;
    veS[n * 128 + i] = v_emb[(size_t)sv[n] * EMB + i];
  }

  // ---- phase 1: q[32][128] = veS @ Wq1^T + qbias; store with head0 negated
  {
    const int tx = tid & 31, ty = tid >> 5;
    float acc[4][4];
#pragma unroll
    for (int r = 0; r < 4; ++r)
#pragma unroll
      for (int c = 0; c < 4; ++c) acc[r][c] = wsf[OFF_QBIAS + tx + 32 * c];
#pragma unroll 1
    for (int kc = 0; kc < 4; ++kc) {
      __syncthreads();  // kc=0: veS ready; kc>0: prev readers done
      for (int idx = tid; idx < 4096; idx += 256) {
        int o = idx >> 5, kk = idx & 31;
        WqS[o * 33 + kk] = Wq[o * 256 + kc * 32 + kk];
      }
      __syncthreads();
#pragma unroll 4
      for (int i = 0; i < 32; ++i) {
        float wv[4], vv[4];
#pragma unroll
        for (int c = 0; c < 4; ++c) wv[c] = WqS[(tx + 32 * c) * 33 + i];
#pragma unroll
        for (int r = 0; r < 4; ++r) vv[r] = veS[(ty + 8 * r) * 128 + kc * 32 + i];
#pragma unroll
        for (int r = 0; r < 4; ++r)
#pragma unroll
          for (int c = 0; c < 4; ++c) acc[r][c] += vv[r] * wv[c];
      }
    }
#pragma unroll
    for (int r = 0; r < 4; ++r)
#pragma unroll
      for (int c = 0; c < 4; ++c)
        q_s[(ty + 8 * r) * 128 + (tx + 32 * c)] =
            (c < 2) ? -acc[r][c] : acc[r][c];  // cols 0..63 = head0 -> negate
  }

  // ---- phase 2: Ad[32][384] = qsign @ Wk (single pass over 128 q-dims) ----
  {
    const int tx = tid & 63, ty = tid >> 6;
    float acc[8][6];
#pragma unroll
    for (int r = 0; r < 8; ++r)
#pragma unroll
      for (int c = 0; c < 6; ++c) acc[r][c] = 0.f;
#pragma unroll 1
    for (int jc = 0; jc < 8; ++jc) {
      __syncthreads();  // jc=0: q_s writes done; later: prev WkS readers done
      for (int idx = tid; idx < 6144; idx += 256) {
        int jj = idx / 384, o = idx - jj * 384;
        WkS[jj * 385 + o] = Wk[(size_t)(jc * 16 + jj) * 384 + o];
      }
      __syncthreads();
#pragma unroll 4
      for (int jj = 0; jj < 16; ++jj) {
        float bb[6], qq[8];
#pragma unroll
        for (int c = 0; c < 6; ++c) bb[c] = WkS[jj * 385 + tx + 64 * c];
#pragma unroll
        for (int r = 0; r < 8; ++r)
          qq[r] = q_s[(ty + 4 * r) * 128 + jc * 16 + jj];
#pragma unroll
        for (int r = 0; r < 8; ++r)
#pragma unroll
          for (int c = 0; c < 6; ++c) acc[r][c] += qq[r] * bb[c];
      }
    }
#pragma unroll
    for (int r = 0; r < 8; ++r) {
      const size_t n = (size_t)(base + ty + 4 * r);
#pragma unroll
      for (int c = 0; c < 6; ++c)
        ABC[n * 384 + tx + 64 * c] = f2bf(acc[r][c]);
    }
  }

  if (tid < 32) {  // QBK[n] = qsign . bk   (q_s stable since phase 1)
    float s = 0.f;
    for (int j = 0; j < 128; ++j) s += q_s[tid * 128 + j] * bk[j];
    QBK[(size_t)(base + tid)] = s;
  }
}

// ---------------------------------------------------------------------------
// K2: 2500 blocks x 4 waves, 10 nodes/wave. Lane l owns dims {2l,2l+1}.
// 3-pass batched edge phase per 10-edge chunk:
//   A: dot partials pd[10] + cos pairs (all independent -> ILP)
//   B: batched butterfly (60 independent shfl chains, pipelined)
//   C: sigmoid + weighted accumulation (independent exps)
// All register arrays statically indexed (chunk loop fully unrolled).
// __launch_bounds__(256,4): cap VGPR 128 -> 4 waves/SIMD.
// ---------------------------------------------------------------------------
__global__ __launch_bounds__(256, 4) void tgn_k2_edge(
    const void* __restrict__ node_data, const int* __restrict__ nbr_data,
    const void* __restrict__ nbr_mask,
    const unsigned* __restrict__ vbf, const unsigned* __restrict__ rbf,
    const float* __restrict__ time_w, const float* __restrict__ time_b,
    const unsigned* __restrict__ abc32, const float* __restrict__ QBK,
    const float* __restrict__ wsf, const float* __restrict__ bc,
    const int* __restrict__ flags, float* __restrict__ out)
{
  __shared__ float cw_s[7680];
  const int tid = threadIdx.x;
  for (int idx = tid; idx < 7680; idx += 256) cw_s[idx] = wsf[OFF_CW + idx];
  __syncthreads();

  const int nd64 = flags[0];
  const int mmode = flags[1];
  const int lane = tid & 63;
  const int gw = blockIdx.x * 4 + (tid >> 6);  // 2500*4 = 10000 waves
  const float2 tw = *(const float2*)(time_w + 2 * lane);
  const float2 tb = *(const float2*)(time_b + 2 * lane);

#pragma unroll 1
  for (int it = 0; it < 10; ++it) {
    const int n = it * 10000 + gw;  // consecutive across waves each iter
    const int t_node = load_node(node_data, (size_t)n * 4 + 2, nd64);

    int e_v = 0, e_r = 0, e_t = 0, e_m = 1;
    if (lane < NBR) {
      const int* p = nbr_data + ((size_t)n * NBR + lane) * 3;
      e_v = p[0]; e_r = p[1]; e_t = p[2];
      e_m = load_mask(nbr_mask, (size_t)n * NBR + lane, mmode);
    }

    // issue ALL 40 gathers up-front (wave-uniform rows; 4B/lane, coalesced)
    unsigned gne[NBR], gre[NBR];
#pragma unroll
    for (int j = 0; j < NBR; ++j) {
      int vv = __shfl(e_v, j, 64);
      int rr = __shfl(e_r, j, 64);
      gne[j] = vbf[(size_t)vv * 64 + lane];
      gre[j] = rbf[(size_t)rr * 64 + lane];
    }

    // difference duals (bf16) + scalar dual bias
    float adx[3], ady[3];
#pragma unroll
    for (int a = 0; a < 3; ++a) {
      float2 v = unpack_bf2(abc32[(size_t)n * 192 + a * 64 + lane]);
      adx[a] = v.x; ady[a] = v.y;
    }
    const float qbkd = QBK[n];

    float sux[3] = {0, 0, 0}, suy[3] = {0, 0, 0};
    float swx[3] = {0, 0, 0}, swy[3] = {0, 0, 0};
    float satt0 = 0.f;

#pragma unroll
    for (int c2 = 0; c2 < 2; ++c2) {  // two chunks of 10 edges (fully unrolled)
      float pd[10], ce0[10], ce1[10];

      // ---- pass A: cos + dot partials + unweighted sums (all independent)
#pragma unroll
      for (int jj = 0; jj < 10; ++jj) {
        const int j = c2 * 10 + jj;
        int tj = __shfl(e_t, j, 64);
        float dt = (float)(t_node - tj);
        // match reference rounding: rn(dt*tw) then rn(+tb); no fma contraction
        ce0[jj] = cosf(__fadd_rn(__fmul_rn(dt, tw.x), tb.x));
        ce1[jj] = cosf(__fadd_rn(__fmul_rn(dt, tw.y), tb.y));
        float2 ne = unpack_bf2(gne[j]);
        float2 re = unpack_bf2(gre[j]);
        pd[jj] = adx[0] * ne.x + ady[0] * ne.y + adx[1] * re.x +
                 ady[1] * re.y + adx[2] * ce0[jj] + ady[2] * ce1[jj];
        sux[0] += ne.x; suy[0] += ne.y;
        sux[1] += re.x; suy[1] += re.y;
        sux[2] += ce0[jj]; suy[2] += ce1[jj];
      }

      // ---- pass B: batched butterfly (independent chains pipeline)
#pragma unroll
      for (int m = 1; m < 64; m <<= 1) {
#pragma unroll
        for (int jj = 0; jj < 10; ++jj) pd[jj] += __shfl_xor(pd[jj], m, 64);
      }

      // ---- pass C: sigmoid + weighted accumulation (independent exps)
#pragma unroll
      for (int jj = 0; jj < 10; ++jj) {
        const int j = c2 * 10 + jj;
        int mj = __shfl(e_m, j, 64);
        float dlt = (pd[jj] + qbkd) * RSQRT128;  // = s1 - s0
        // softmax over 2 heads == sigmoid; masked edges: both -1e9 -> 0.5
        float att0 = mj ? 0.5f : 1.0f / (1.0f + __expf(dlt));
        satt0 += att0;
        float2 ne = unpack_bf2(gne[j]);
        float2 re = unpack_bf2(gre[j]);
        swx[0] += att0 * ne.x; swy[0] += att0 * ne.y;
        swx[1] += att0 * re.x; swy[1] += att0 * re.y;
        swx[2] += att0 * ce0[jj]; swy[2] += att0 * ce1[jj];
      }
    }

    unsigned long long alive = __ballot(lane < NBR && !e_m);
    bool flag = (alive == 0ULL);  // all masked -> out zeroed -> logits = bc

    // head1 sums = unweighted - head0 sums
    float s1x[3], s1y[3];
#pragma unroll
    for (int a = 0; a < 3; ++a) {
      s1x[a] = sux[a] - swx[a];
      s1y[a] = suy[a] - swy[a];
    }

    float lg[10];
#pragma unroll
    for (int c = 0; c < 10; ++c) {
      float p = 0.f;
#pragma unroll
      for (int a = 0; a < 3; ++a) {
        const float* c0 = &cw_s[((a * 2 + 0) * 10 + c) * 128 + 2 * lane];
        const float* c1 = &cw_s[((a * 2 + 1) * 10 + c) * 128 + 2 * lane];
        p += c0[0] * swx[a] + c0[1] * swy[a] + c1[0] * s1x[a] + c1[1] * s1y[a];
      }
#pragma unroll
      for (int m = 1; m < 64; m <<= 1) p += __shfl_xor(p, m, 64);
      lg[c] = p;
    }
    if (lane == 0) {
      const float satt1 = (float)NBR - satt0;
#pragma unroll
      for (int c = 0; c < 10; ++c) {
        float v;
        if (flag) v = bc[c];
        else
          v = lg[c] + satt0 * wsf[OFF_CB + c] + satt1 * wsf[OFF_CB + 10 + c] +
              wsf[OFF_C10 + c];
        out[(size_t)n * 10 + c] = v;
      }
    }
  }
}

// ---------------------------------------------------------------------------
extern "C" void kernel_launch(void* const* d_in, const int* in_sizes, int n_in,
                              void* d_out, int out_size, void* d_ws,
                              size_t ws_size, hipStream_t stream)
{
  const void* node_data = d_in[0];
  const int* nbr_data = (const int*)d_in[1];
  const void* nbr_mask = d_in[2];
  const float* v_emb = (const float*)d_in[3];
  const float* r_emb = (const float*)d_in[4];
  const float* time_w = (const float*)d_in[5];
  const float* time_b = (const float*)d_in[6];
  const float* Wq = (const float*)d_in[7];
  const float* bq = (const float*)d_in[8];
  const float* Wk = (const float*)d_in[9];
  const float* bk = (const float*)d_in[10];
  const float* Wv = (const float*)d_in[11];
  const float* bv = (const float*)d_in[12];
  const float* Wo = (const float*)d_in[13];
  const float* bo = (const float*)d_in[14];
  const float* Wc = (const float*)d_in[15];
  const float* bc = (const float*)d_in[16];
  float* out = (float*)d_out;
  float* wsf = (float*)d_ws;
  int* flags = (int*)((char*)d_ws + OFF_FLAGS * sizeof(float));

  unsigned short* ABC = (unsigned short*)((char*)d_ws + OFF_ABC);
  float* QBK = (float*)((char*)d_ws + OFF_QBK);
  unsigned* vbf = (unsigned*)((char*)d_ws + OFF_VBF);
  unsigned* rbf = (unsigned*)((char*)d_ws + OFF_RBF);

  hipLaunchKernelGGL(tgn_detect, dim3(1), dim3(256), 0, stream,
                     (const int*)node_data, (const unsigned char*)nbr_mask,
                     flags);
  hipLaunchKernelGGL(tgn_k0_prep, dim3(1), dim3(256), 0, stream, Wq, bq,
                     time_b, Wv, bv, Wo, bo, Wc, bc, wsf);
  hipLaunchKernelGGL(tgn_cvt, dim3(2048), dim3(256), 0, stream, v_emb, vbf,
                     100000 * 64);
  hipLaunchKernelGGL(tgn_cvt, dim3(2048), dim3(256), 0, stream, r_emb, rbf,
                     100000 * 64);
  hipLaunchKernelGGL(tgn_k1_abc, dim3(3125), dim3(256), 12416 * sizeof(float),
                     stream, node_data, v_emb, Wq, Wk, bk, wsf, flags, ABC,
                     QBK);
  hipLaunchKernelGGL(tgn_k2_edge, dim3(2500), dim3(256), 0, stream, node_data,
                     nbr_data, nbr_mask, vbf, rbf, time_w, time_b,
                     (const unsigned*)ABC, QBK, wsf, bc, flags, out);
}

// Round 6
// 1527.136 us; speedup vs baseline: 1.7859x; 1.7859x over previous
//
#include <hip/hip_runtime.h>
#include <hip/hip_bf16.h>

// ---------------------------------------------------------------------------
// TGN neighbor attention. Key algebra:
//   softmax over HEADS(=2) per edge  =>  att0 = sigmoid(s0-s1), att1 = 1-att0
//   => only the DIFFERENCE dual Ad = A1-A0 is needed for scores:
//      Ad = qsign @ Wk, qsign = [-q0 | +q1];  s1-s0 = (Ad.keyv + qbkd)/sqrt(128)
//   S_0,arr = att0-weighted sums; S_1,arr = (unweighted) - S_0,arr
//   satt1 = 20 - satt0
//   logits = sum_r CW_r @ S_r + satt0*cb0 + (20-satt0)*cb1 + c10
// Kd: dtype detect. K0: constants. Kc: v/r_emb -> bf16 tables.
// K1: per-node qsign -> Ad table (bf16) + qbkd.
// K2 (this round): chunk-5 software-pipelined edge phase. Round-5 lesson:
//     __launch_bounds__(256,4) clamped VGPR to 64 -> 2.1 GB spill stores
//     (WRITE_SIZE) + 3.2 GB spill reloads. Fix: named double-buffer gathers
//     (20 regs live, statically indexed), default launch bounds, no clamp.
// ---------------------------------------------------------------------------

#define N_NODES 100000
#define EMB 128
#define NBR 20
#define CLS 10

// ws float-offsets for the small constant region
#define OFF_QBIAS 0            // 128
#define OFF_CW    128          // 6*10*128 = 7680, layout ((arr*2+h)*10+c)*128+d
#define OFF_CB    (128 + 7680) // 20: [h][c]
#define OFF_C10   (OFF_CB + 20)// 10
#define OFF_FLAGS 8000         // 2 ints (byte off 32000)
// byte offsets of the big ws tables
#define OFF_ABC 32768ULL                          // 100000*384*2 = 76.8 MB
#define OFF_QBK (OFF_ABC + 100000ULL * 384 * 2)   // 0.4 MB
#define OFF_VBF (OFF_QBK + 100000ULL * 4)         // 25.6 MB
#define OFF_RBF (OFF_VBF + 100000ULL * 128 * 2)   // 25.6 MB

#define RSQRT128 0.08838834764831845f

// round-to-nearest-even f32 -> bf16 bits
__device__ __forceinline__ unsigned short f2bf(float x) {
  unsigned u = __float_as_uint(x);
  return (unsigned short)((u + 0x7fffu + ((u >> 16) & 1u)) >> 16);
}
// unpack 2 bf16 (packed little-endian in a uint) -> float2
__device__ __forceinline__ float2 unpack_bf2(unsigned u) {
  float2 f;
  f.x = __uint_as_float(u << 16);
  f.y = __uint_as_float(u & 0xffff0000u);
  return f;
}

// ---- dtype-flexible loads (flags decided by tgn_detect at runtime) --------
__device__ __forceinline__ int load_node(const void* nd, size_t idx, int is64) {
  if (is64) return (int)((const long long*)nd)[idx];
  return ((const int*)nd)[idx];
}
// mode: 0=u8, 1=i32, 2=i64, 3=f32
__device__ __forceinline__ int load_mask(const void* m, size_t idx, int mode) {
  if (mode == 0) return ((const unsigned char*)m)[idx] != 0;
  if (mode == 1) return ((const int*)m)[idx] != 0;
  if (mode == 2) return ((const long long*)m)[idx] != 0;
  return ((const float*)m)[idx] != 0.0f;
}

// ---------------------------------------------------------------------------
__global__ __launch_bounds__(256) void tgn_detect(
    const int* __restrict__ nd, const unsigned char* __restrict__ m,
    int* __restrict__ flags)
{
  __shared__ int s_odd, s_b123, s_b4, s_bgt;
  const int tid = threadIdx.x;
  if (tid == 0) { s_odd = 0; s_b123 = 0; s_b4 = 0; s_bgt = 0; }
  __syncthreads();
  int odd = 0;
  for (int i = 2 * tid + 1; i < 4096; i += 512) odd |= nd[i];
  int b123 = 0, b4 = 0, bgt = 0;
  for (int i = tid * 4; i < 8192; i += 1024) {
    b123 |= m[i + 1] | m[i + 2] | m[i + 3];
    bgt |= (m[i] > 1) | (m[i + 1] > 1) | (m[i + 2] > 1) | (m[i + 3] > 1);
  }
  for (int i = tid * 8 + 4; i < 8192; i += 2048) b4 |= m[i];
  if (odd) atomicOr(&s_odd, 1);
  if (b123) atomicOr(&s_b123, 1);
  if (b4) atomicOr(&s_b4, 1);
  if (bgt) atomicOr(&s_bgt, 1);
  __syncthreads();
  if (tid == 0) {
    flags[0] = (s_odd == 0) ? 1 : 0;  // node_data is int64
    flags[1] = s_bgt ? 3 : (s_b123 ? 0 : (s_b4 ? 1 : 2));
  }
}

// ---------------------------------------------------------------------------
// Kc: fp32 -> packed bf16x2 table conversion (grid-stride over float2 pairs)
// ---------------------------------------------------------------------------
__global__ __launch_bounds__(256) void tgn_cvt(
    const float* __restrict__ src, unsigned* __restrict__ dst, int npair)
{
  int i = blockIdx.x * 256 + threadIdx.x;
  const int stride = gridDim.x * 256;
  for (; i < npair; i += stride) {
    float2 f = ((const float2*)src)[i];
    dst[i] = (unsigned)f2bf(f.x) | ((unsigned)f2bf(f.y) << 16);
  }
}

// ---------------------------------------------------------------------------
// K0: one block. qbias = Wq[:,128:]@cos(time_b)+bq ; M = Wc@Wo ;
// CW[arr*2+h] = M_h @ Wv[h-rows, arr-block] ; cb[h]=M_h@bv_h ; c10=Wc@bo+bc
// ---------------------------------------------------------------------------
__global__ __launch_bounds__(256) void tgn_k0_prep(
    const float* __restrict__ Wq, const float* __restrict__ bq,
    const float* __restrict__ time_b,
    const float* __restrict__ Wv, const float* __restrict__ bv,
    const float* __restrict__ Wo, const float* __restrict__ bo,
    const float* __restrict__ Wc, const float* __restrict__ bc,
    float* __restrict__ wsf)
{
  __shared__ float ccos[128];
  __shared__ float sM[10 * 128];
  const int tid = threadIdx.x;
  if (tid < 128) ccos[tid] = cosf(time_b[tid]);
  __syncthreads();
  if (tid < 128) {
    float s = bq[tid];
    for (int j = 0; j < 128; ++j) s += Wq[tid * 256 + 128 + j] * ccos[j];
    wsf[OFF_QBIAS + tid] = s;
  }
  for (int idx = tid; idx < 1280; idx += 256) {   // M = Wc @ Wo  (10x128)
    int c = idx >> 7, i = idx & 127;
    float s = 0.f;
    for (int k = 0; k < 128; ++k) s += Wc[c * 128 + k] * Wo[k * 128 + i];
    sM[idx] = s;
  }
  __syncthreads();
  for (int idx = tid; idx < 7680; idx += 256) {   // CW composites
    int r = idx / 1280;
    int c = (idx >> 7) % 10;
    int d = idx & 127;
    int arr = r >> 1, h = r & 1;
    float s = 0.f;
    for (int k = 0; k < 64; ++k)
      s += sM[c * 128 + h * 64 + k] * Wv[(h * 64 + k) * 384 + arr * 128 + d];
    wsf[OFF_CW + idx] = s;
  }
  if (tid < 20) {                                  // cb[h][c]
    int h = tid / 10, c = tid % 10;
    float s = 0.f;
    for (int k = 0; k < 64; ++k) s += sM[c * 128 + h * 64 + k] * bv[h * 64 + k];
    wsf[OFF_CB + tid] = s;
  }
  if (tid < 10) {                                  // c10 = Wc@bo + bc
    float s = 0.f;
    for (int k = 0; k < 128; ++k) s += Wc[tid * 128 + k] * bo[k];
    wsf[OFF_C10 + tid] = s + bc[tid];
  }
}

// ---------------------------------------------------------------------------
// K1: 32 nodes/block.
// Phase1: q = Wq1@ve + qbias (Wq1 staged in 4 K-chunks [128][33]); store
//         qsign into q_s (negate dims<64 = head0).
// Phase2: Ad[32][384] = qsign @ Wk, Wk staged in 8 chunks of 16 rows
//         ([16][385]); store bf16 to ABC[n*384+i].
// QBK[n] = qsign . bk.   Dynamic LDS 12416 floats = 49664 B (<64 KB cap).
// ---------------------------------------------------------------------------
__global__ __launch_bounds__(256) void tgn_k1_abc(
    const void* __restrict__ node_data, const float* __restrict__ v_emb,
    const float* __restrict__ Wq, const float* __restrict__ Wk,
    const float* __restrict__ bk, const float* __restrict__ wsf,
    const int* __restrict__ flags, unsigned short* __restrict__ ABC,
    float* __restrict__ QBK)
{
  extern __shared__ float smem[];
  float* WqS = smem;          // [128][33]
  float* veS = smem + 4224;   // [32][128]
  float* WkS = smem;          // [16][385]
  float* q_s = smem + 8320;   // [32][128]
  __shared__ int sv[32];
  const int tid = threadIdx.x;
  const int base = blockIdx.x * 32;  // 3125 * 32 == 100000 exactly
  const int nd64 = flags[0];

  if (tid < 32) sv[tid] = load_node(node_data, (size_t)(base + tid) * 4, nd64);
  __syncthreads();
  for (int idx = tid; idx < 4096; idx += 256) {
    int n = idx >> 7, i = idx & 127;
    veS[n * 128 + i] = v_emb[(size_t)sv[n] * EMB + i];
  }

  // ---- phase 1: q[32][128] = veS @ Wq1^T + qbias; store with head0 negated
  {
    const int tx = tid & 31, ty = tid >> 5;
    float acc[4][4];
#pragma unroll
    for (int r = 0; r < 4; ++r)
#pragma unroll
      for (int c = 0; c < 4; ++c) acc[r][c] = wsf[OFF_QBIAS + tx + 32 * c];
#pragma unroll 1
    for (int kc = 0; kc < 4; ++kc) {
      __syncthreads();  // kc=0: veS ready; kc>0: prev readers done
      for (int idx = tid; idx < 4096; idx += 256) {
        int o = idx >> 5, kk = idx & 31;
        WqS[o * 33 + kk] = Wq[o * 256 + kc * 32 + kk];
      }
      __syncthreads();
#pragma unroll 4
      for (int i = 0; i < 32; ++i) {
        float wv[4], vv[4];
#pragma unroll
        for (int c = 0; c < 4; ++c) wv[c] = WqS[(tx + 32 * c) * 33 + i];
#pragma unroll
        for (int r = 0; r < 4; ++r) vv[r] = veS[(ty + 8 * r) * 128 + kc * 32 + i];
#pragma unroll
        for (int r = 0; r < 4; ++r)
#pragma unroll
          for (int c = 0; c < 4; ++c) acc[r][c] += vv[r] * wv[c];
      }
    }
#pragma unroll
    for (int r = 0; r < 4; ++r)
#pragma unroll
      for (int c = 0; c < 4; ++c)
        q_s[(ty + 8 * r) * 128 + (tx + 32 * c)] =
            (c < 2) ? -acc[r][c] : acc[r][c];  // cols 0..63 = head0 -> negate
  }

  // ---- phase 2: Ad[32][384] = qsign @ Wk (single pass over 128 q-dims) ----
  {
    const int tx = tid & 63, ty = tid >> 6;
    float acc[8][6];
#pragma unroll
    for (int r = 0; r < 8; ++r)
#pragma unroll
      for (int c = 0; c < 6; ++c) acc[r][c] = 0.f;
#pragma unroll 1
    for (int jc = 0; jc < 8; ++jc) {
      __syncthreads();  // jc=0: q_s writes done; later: prev WkS readers done
      for (int idx = tid; idx < 6144; idx += 256) {
        int jj = idx / 384, o = idx - jj * 384;
        WkS[jj * 385 + o] = Wk[(size_t)(jc * 16 + jj) * 384 + o];
      }
      __syncthreads();
#pragma unroll 4
      for (int jj = 0; jj < 16; ++jj) {
        float bb[6], qq[8];
#pragma unroll
        for (int c = 0; c < 6; ++c) bb[c] = WkS[jj * 385 + tx + 64 * c];
#pragma unroll
        for (int r = 0; r < 8; ++r)
          qq[r] = q_s[(ty + 4 * r) * 128 + jc * 16 + jj];
#pragma unroll
        for (int r = 0; r < 8; ++r)
#pragma unroll
          for (int c = 0; c < 6; ++c) acc[r][c] += qq[r] * bb[c];
      }
    }
#pragma unroll
    for (int r = 0; r < 8; ++r) {
      const size_t n = (size_t)(base + ty + 4 * r);
#pragma unroll
      for (int c = 0; c < 6; ++c)
        ABC[n * 384 + tx + 64 * c] = f2bf(acc[r][c]);
    }
  }

  if (tid < 32) {  // QBK[n] = qsign . bk   (q_s stable since phase 1)
    float s = 0.f;
    for (int j = 0; j < 128; ++j) s += q_s[tid * 128 + j] * bk[j];
    QBK[(size_t)(base + tid)] = s;
  }
}

// ---------------------------------------------------------------------------
// K2: 2500 blocks x 4 waves, 10 nodes/wave. Lane l owns dims {2l,2l+1}.
// Chunk-5 software pipeline with NAMED double buffers (static indexing,
// rule #20): prefetch chunk c+1 gathers while computing chunk c.
// Per chunk: pass A (5 indep dot partials + cos), pass B (batched butterfly,
// 5 indep 6-deep shfl chains), pass C (5 indep sigmoids + accums).
// Default launch bounds — Round 5's (256,4) clamp caused 5.4 GB spill traffic.
// ---------------------------------------------------------------------------
#define ISSUE5(BUF, C)                                              \
  _Pragma("unroll")                                                 \
  for (int jj = 0; jj < 5; ++jj) {                                  \
    int vv = __shfl(e_v, (C) * 5 + jj, 64);                         \
    int rr = __shfl(e_r, (C) * 5 + jj, 64);                         \
    BUF##ne[jj] = vbf[(size_t)vv * 64 + lane];                      \
    BUF##re[jj] = rbf[(size_t)rr * 64 + lane];                      \
  }

#define PROC5(BUF, C)                                                        \
  {                                                                          \
    float pd[5], ce0[5], ce1[5];                                             \
    _Pragma("unroll")                                                        \
    for (int jj = 0; jj < 5; ++jj) {                                         \
      int tj = __shfl(e_t, (C) * 5 + jj, 64);                                \
      float dt = (float)(t_node - tj);                                       \
      ce0[jj] = cosf(__fadd_rn(__fmul_rn(dt, tw.x), tb.x));                  \
      ce1[jj] = cosf(__fadd_rn(__fmul_rn(dt, tw.y), tb.y));                  \
      float2 ne = unpack_bf2(BUF##ne[jj]);                                   \
      float2 re = unpack_bf2(BUF##re[jj]);                                   \
      pd[jj] = adx[0] * ne.x + ady[0] * ne.y + adx[1] * re.x +               \
               ady[1] * re.y + adx[2] * ce0[jj] + ady[2] * ce1[jj];          \
      sux0 += ne.x; suy0 += ne.y;                                            \
      sux1 += re.x; suy1 += re.y;                                            \
      sux2 += ce0[jj]; suy2 += ce1[jj];                                      \
    }                                                                        \
    _Pragma("unroll")                                                        \
    for (int m = 1; m < 64; m <<= 1) {                                       \
      _Pragma("unroll")                                                      \
      for (int jj = 0; jj < 5; ++jj) pd[jj] += __shfl_xor(pd[jj], m, 64);    \
    }                                                                        \
    _Pragma("unroll")                                                        \
    for (int jj = 0; jj < 5; ++jj) {                                         \
      int mj = __shfl(e_m, (C) * 5 + jj, 64);                                \
      float dlt = (pd[jj] + qbkd) * RSQRT128;                                \
      float att0 = mj ? 0.5f : 1.0f / (1.0f + __expf(dlt));                  \
      satt0 += att0;                                                         \
      float2 ne = unpack_bf2(BUF##ne[jj]);                                   \
      float2 re = unpack_bf2(BUF##re[jj]);                                   \
      swx0 += att0 * ne.x; swy0 += att0 * ne.y;                              \
      swx1 += att0 * re.x; swy1 += att0 * re.y;                              \
      swx2 += att0 * ce0[jj]; swy2 += att0 * ce1[jj];                        \
    }                                                                        \
  }

__global__ __launch_bounds__(256) void tgn_k2_edge(
    const void* __restrict__ node_data, const int* __restrict__ nbr_data,
    const void* __restrict__ nbr_mask,
    const unsigned* __restrict__ vbf, const unsigned* __restrict__ rbf,
    const float* __restrict__ time_w, const float* __restrict__ time_b,
    const unsigned* __restrict__ abc32, const float* __restrict__ QBK,
    const float* __restrict__ wsf, const float* __restrict__ bc,
    const int* __restrict__ flags, float* __restrict__ out)
{
  __shared__ float cw_s[7680];
  const int tid = threadIdx.x;
  for (int idx = tid; idx < 7680; idx += 256) cw_s[idx] = wsf[OFF_CW + idx];
  __syncthreads();

  const int nd64 = flags[0];
  const int mmode = flags[1];
  const int lane = tid & 63;
  const int gw = blockIdx.x * 4 + (tid >> 6);  // 2500*4 = 10000 waves
  const float2 tw = *(const float2*)(time_w + 2 * lane);
  const float2 tb = *(const float2*)(time_b + 2 * lane);

#pragma unroll 1
  for (int it = 0; it < 10; ++it) {
    const int n = it * 10000 + gw;  // consecutive across waves each iter
    const int t_node = load_node(node_data, (size_t)n * 4 + 2, nd64);

    int e_v = 0, e_r = 0, e_t = 0, e_m = 1;
    if (lane < NBR) {
      const int* p = nbr_data + ((size_t)n * NBR + lane) * 3;
      e_v = p[0]; e_r = p[1]; e_t = p[2];
      e_m = load_mask(nbr_mask, (size_t)n * NBR + lane, mmode);
    }

    // difference duals (bf16) + scalar dual bias
    float adx[3], ady[3];
#pragma unroll
    for (int a = 0; a < 3; ++a) {
      float2 v = unpack_bf2(abc32[(size_t)n * 192 + a * 64 + lane]);
      adx[a] = v.x; ady[a] = v.y;
    }
    const float qbkd = QBK[n];

    float sux0 = 0, sux1 = 0, sux2 = 0, suy0 = 0, suy1 = 0, suy2 = 0;
    float swx0 = 0, swx1 = 0, swx2 = 0, swy0 = 0, swy1 = 0, swy2 = 0;
    float satt0 = 0.f;

    // chunk-5 software pipeline: named double buffers, fully static indexing
    unsigned Ane[5], Are[5], Bne[5], Bre[5];
    ISSUE5(A, 0)
    ISSUE5(B, 1)
    PROC5(A, 0)
    ISSUE5(A, 2)
    PROC5(B, 1)
    ISSUE5(B, 3)
    PROC5(A, 2)
    PROC5(B, 3)

    unsigned long long alive = __ballot(lane < NBR && !e_m);
    bool flag = (alive == 0ULL);  // all masked -> out zeroed -> logits = bc

    // head1 sums = unweighted - head0 sums
    const float s1x0 = sux0 - swx0, s1y0 = suy0 - swy0;
    const float s1x1 = sux1 - swx1, s1y1 = suy1 - swy1;
    const float s1x2 = sux2 - swx2, s1y2 = suy2 - swy2;

    float lg[10];
#pragma unroll
    for (int c = 0; c < 10; ++c) {
      const float* c00 = &cw_s[((0 * 2 + 0) * 10 + c) * 128 + 2 * lane];
      const float* c01 = &cw_s[((0 * 2 + 1) * 10 + c) * 128 + 2 * lane];
      const float* c10 = &cw_s[((1 * 2 + 0) * 10 + c) * 128 + 2 * lane];
      const float* c11 = &cw_s[((1 * 2 + 1) * 10 + c) * 128 + 2 * lane];
      const float* c20 = &cw_s[((2 * 2 + 0) * 10 + c) * 128 + 2 * lane];
      const float* c21 = &cw_s[((2 * 2 + 1) * 10 + c) * 128 + 2 * lane];
      float p = c00[0] * swx0 + c00[1] * swy0 + c01[0] * s1x0 + c01[1] * s1y0 +
                c10[0] * swx1 + c10[1] * swy1 + c11[0] * s1x1 + c11[1] * s1y1 +
                c20[0] * swx2 + c20[1] * swy2 + c21[0] * s1x2 + c21[1] * s1y2;
#pragma unroll
      for (int m = 1; m < 64; m <<= 1) p += __shfl_xor(p, m, 64);
      lg[c] = p;
    }
    if (lane == 0) {
      const float satt1 = (float)NBR - satt0;
#pragma unroll
      for (int c = 0; c < 10; ++c) {
        float v;
        if (flag) v = bc[c];
        else
          v = lg[c] + satt0 * wsf[OFF_CB + c] + satt1 * wsf[OFF_CB + 10 + c] +
              wsf[OFF_C10 + c];
        out[(size_t)n * 10 + c] = v;
      }
    }
  }
}

// ---------------------------------------------------------------------------
extern "C" void kernel_launch(void* const* d_in, const int* in_sizes, int n_in,
                              void* d_out, int out_size, void* d_ws,
                              size_t ws_size, hipStream_t stream)
{
  const void* node_data = d_in[0];
  const int* nbr_data = (const int*)d_in[1];
  const void* nbr_mask = d_in[2];
  const float* v_emb = (const float*)d_in[3];
  const float* r_emb = (const float*)d_in[4];
  const float* time_w = (const float*)d_in[5];
  const float* time_b = (const float*)d_in[6];
  const float* Wq = (const float*)d_in[7];
  const float* bq = (const float*)d_in[8];
  const float* Wk = (const float*)d_in[9];
  const float* bk = (const float*)d_in[10];
  const float* Wv = (const float*)d_in[11];
  const float* bv = (const float*)d_in[12];
  const float* Wo = (const float*)d_in[13];
  const float* bo = (const float*)d_in[14];
  const float* Wc = (const float*)d_in[15];
  const float* bc = (const float*)d_in[16];
  float* out = (float*)d_out;
  float* wsf = (float*)d_ws;
  int* flags = (int*)((char*)d_ws + OFF_FLAGS * sizeof(float));

  unsigned short* ABC = (unsigned short*)((char*)d_ws + OFF_ABC);
  float* QBK = (float*)((char*)d_ws + OFF_QBK);
  unsigned* vbf = (unsigned*)((char*)d_ws + OFF_VBF);
  unsigned* rbf = (unsigned*)((char*)d_ws + OFF_RBF);

  hipLaunchKernelGGL(tgn_detect, dim3(1), dim3(256), 0, stream,
                     (const int*)node_data, (const unsigned char*)nbr_mask,
                     flags);
  hipLaunchKernelGGL(tgn_k0_prep, dim3(1), dim3(256), 0, stream, Wq, bq,
                     time_b, Wv, bv, Wo, bo, Wc, bc, wsf);
  hipLaunchKernelGGL(tgn_cvt, dim3(2048), dim3(256), 0, stream, v_emb, vbf,
                     100000 * 64);
  hipLaunchKernelGGL(tgn_cvt, dim3(2048), dim3(256), 0, stream, r_emb, rbf,
                     100000 * 64);
  hipLaunchKernelGGL(tgn_k1_abc, dim3(3125), dim3(256), 12416 * sizeof(float),
                     stream, node_data, v_emb, Wq, Wk, bk, wsf, flags, ABC,
                     QBK);
  hipLaunchKernelGGL(tgn_k2_edge, dim3(2500), dim3(256), 0, stream, node_data,
                     nbr_data, nbr_mask, vbf, rbf, time_w, time_b,
                     (const unsigned*)ABC, QBK, wsf, bc, flags, out);
}